// Round 1
// baseline (929.456 us; speedup 1.0000x reference)
//
#include <hip/hip_runtime.h>

// GCN: N=100000 nodes, E=1600000 edges, dims 128 -> 64 -> 32.
// out1 = relu(dinv * segsum(g1) + b1), g1 = dinv * (x@W1), segsum includes self-loop g1[i]
// out  =       dinv * segsum(g2) + b2, g2 = dinv * (h1@W2)

#define NNODES 100000
#define NEDGES 1600000
#define IN_DIM 128
#define HID 64
#define OUTD 32

__global__ void k_init_deg(float* __restrict__ deg) {
    int i = blockIdx.x * blockDim.x + threadIdx.x;
    if (i < NNODES) deg[i] = 1.0f;  // self-loop
}

__global__ void k_count_deg(const int* __restrict__ col, float* __restrict__ deg) {
    int e = blockIdx.x * blockDim.x + threadIdx.x;
    if (e < NEDGES) atomicAdd(&deg[col[e]], 1.0f);
}

__global__ void k_rsqrt(float* __restrict__ deg) {
    int i = blockIdx.x * blockDim.x + threadIdx.x;
    if (i < NNODES) deg[i] = rsqrtf(deg[i]);
}

// h = x @ W1 ; g1 = dinv*h ; acc1 = g1 (self-loop contribution pre-seeded)
// one thread per (node i, hidden j); 64 consecutive lanes share a node row.
__global__ void k_gemm1(const float* __restrict__ x, const float* __restrict__ W1,
                        const float* __restrict__ dinv,
                        float* __restrict__ g1, float* __restrict__ acc1) {
    int t = blockIdx.x * blockDim.x + threadIdx.x;
    int i = t >> 6;
    int j = t & 63;
    if (i >= NNODES) return;
    const float* xr = x + (size_t)i * IN_DIM;
    float s = 0.0f;
#pragma unroll 8
    for (int k = 0; k < IN_DIM; ++k) {
        s = fmaf(xr[k], W1[k * HID + j], s);  // xr[k] broadcast, W1 row coalesced (L1-hot, 32KB)
    }
    float g = dinv[i] * s;
    size_t o = (size_t)i * HID + j;
    g1[o] = g;
    acc1[o] = g;
}

// one lane per (edge, feature j): gather g1[row] (coalesced 256B random segment),
// atomicAdd into acc1[col] (coalesced 256B random segment).
__global__ void k_scatter1(const int* __restrict__ row, const int* __restrict__ col,
                           const float* __restrict__ g1, float* __restrict__ acc1) {
    int t = blockIdx.x * blockDim.x + threadIdx.x;
    int e = t >> 6;
    int j = t & 63;
    if (e >= NEDGES) return;
    int r = row[e];
    int c = col[e];
    atomicAdd(&acc1[(size_t)c * HID + j], g1[(size_t)r * HID + j]);
}

// h1 = relu(dinv*acc1 + b1) ; g2 = dinv*(h1 @ W2) ; acc2 = g2
// one thread per (node i, out j2); 32 consecutive lanes share a node row.
__global__ void k_gemm2(const float* __restrict__ acc1, const float* __restrict__ b1,
                        const float* __restrict__ W2, const float* __restrict__ dinv,
                        float* __restrict__ g2, float* __restrict__ acc2) {
    int t = blockIdx.x * blockDim.x + threadIdx.x;
    int i = t >> 5;
    int j2 = t & 31;
    if (i >= NNODES) return;
    float di = dinv[i];
    float s = 0.0f;
#pragma unroll 8
    for (int j = 0; j < HID; ++j) {
        float a = fmaf(di, acc1[(size_t)i * HID + j], b1[j]);
        a = fmaxf(a, 0.0f);                       // relu
        s = fmaf(a, W2[j * OUTD + j2], s);        // W2 L1-hot (8KB)
    }
    float g = di * s;
    size_t o = (size_t)i * OUTD + j2;
    g2[o] = g;
    acc2[o] = g;
}

__global__ void k_scatter2(const int* __restrict__ row, const int* __restrict__ col,
                           const float* __restrict__ g2, float* __restrict__ acc2) {
    int t = blockIdx.x * blockDim.x + threadIdx.x;
    int e = t >> 5;
    int j = t & 31;
    if (e >= NEDGES) return;
    int r = row[e];
    int c = col[e];
    atomicAdd(&acc2[(size_t)c * OUTD + j], g2[(size_t)r * OUTD + j]);
}

__global__ void k_final(const float* __restrict__ acc2, const float* __restrict__ b2,
                        const float* __restrict__ dinv, float* __restrict__ out) {
    int t = blockIdx.x * blockDim.x + threadIdx.x;
    int i = t >> 5;
    int j = t & 31;
    if (i >= NNODES) return;
    out[t] = fmaf(dinv[i], acc2[t], b2[j]);
}

extern "C" void kernel_launch(void* const* d_in, const int* in_sizes, int n_in,
                              void* d_out, int out_size, void* d_ws, size_t ws_size,
                              hipStream_t stream) {
    const float* x  = (const float*)d_in[0];
    const int*   ei = (const int*)d_in[1];   // [2, E] int
    const float* W1 = (const float*)d_in[2];
    const float* b1 = (const float*)d_in[3];
    const float* W2 = (const float*)d_in[4];
    const float* b2 = (const float*)d_in[5];
    float* out = (float*)d_out;

    const int* row = ei;            // edge_index[0] = source
    const int* col = ei + NEDGES;   // edge_index[1] = target

    // workspace layout (ws re-poisoned every launch -> init everything ourselves)
    char* ws = (char*)d_ws;
    float* dinv = (float*)ws;
    size_t off = ((size_t)NNODES * 4 + 511) & ~(size_t)511;
    float* g1   = (float*)(ws + off); off += (size_t)NNODES * HID * 4;
    float* acc1 = (float*)(ws + off); off += (size_t)NNODES * HID * 4;
    float* g2   = (float*)(ws + off); off += (size_t)NNODES * OUTD * 4;
    float* acc2 = g1;  // alias: g1 is dead after k_scatter1 completes

    const int B = 256;
    k_init_deg<<<(NNODES + B - 1) / B, B, 0, stream>>>(dinv);
    k_count_deg<<<(NEDGES + B - 1) / B, B, 0, stream>>>(col, dinv);
    k_rsqrt<<<(NNODES + B - 1) / B, B, 0, stream>>>(dinv);

    {
        long long tot = (long long)NNODES * HID;
        k_gemm1<<<(int)((tot + B - 1) / B), B, 0, stream>>>(x, W1, dinv, g1, acc1);
    }
    {
        long long tot = (long long)NEDGES * HID;
        k_scatter1<<<(int)((tot + B - 1) / B), B, 0, stream>>>(row, col, g1, acc1);
    }
    {
        long long tot = (long long)NNODES * OUTD;
        k_gemm2<<<(int)((tot + B - 1) / B), B, 0, stream>>>(acc1, b1, W2, dinv, g2, acc2);
    }
    {
        long long tot = (long long)NEDGES * OUTD;
        k_scatter2<<<(int)((tot + B - 1) / B), B, 0, stream>>>(row, col, g2, acc2);
    }
    {
        long long tot = (long long)NNODES * OUTD;
        k_final<<<(int)((tot + B - 1) / B), B, 0, stream>>>(acc2, b2, dinv, out);
    }
}